// Round 14
// baseline (185.604 us; speedup 1.0000x reference)
//
#include <hip/hip_runtime.h>
#include <hip/hip_fp16.h>

#define N_NODES 50000
#define N_EDGES 800000
#define IN_DIM 128
#define HID_DIM 64
#define OUT_DIM 64
#define NUM_GRAPHS 512
#define CAP 64      // per-dst bucket capacity; deg ~ Binom(8e5,1/5e4), max ~40
#define NB 196      // coarse buckets = dst>>8  (49999>>8 = 195)
#define BCAP 5120   // coarse bucket capacity (avg 4082, +16 sigma)
#define FILL_T 2048 // edges per coarse-fill block
#define NFILL ((N_EDGES + FILL_T - 1) / FILL_T)  // 391

typedef unsigned short u16;
typedef unsigned int u32;

// ---- hybrid: even blocks = layer-1 GEMM (unscaled fp16 out),
//              odd blocks  = coarse bucket-sort of edges (block-exclusive
//              reserved runs -> L2 merges writes; no line bouncing) ---------
__global__ __launch_bounds__(256) void gemm1_fill_kernel(
    const float* __restrict__ X, const float* __restrict__ W,
    const float* __restrict__ bias, __half* __restrict__ Yh, int n_nodes,
    const int* __restrict__ src, const int* __restrict__ dst,
    int* __restrict__ gcursor, u32* __restrict__ packed, int n_edges) {
    __shared__ float xs[16][IN_DIM];
    __shared__ int hist[256], cnt2[256], goffs[256];
    const int tid = threadIdx.x;

    if (blockIdx.x & 1) {  // ---- coarse fill role ----
        const int fb = blockIdx.x >> 1;
        if (fb >= NFILL) return;
        hist[tid] = 0; cnt2[tid] = 0;
        __syncthreads();
        const int base = fb * FILL_T;
        int d[8], s[8];
#pragma unroll
        for (int i = 0; i < 8; ++i) {
            int e = base + i * 256 + tid;
            if (e < n_edges) {
                d[i] = dst[e]; s[i] = src[e];
                atomicAdd(&hist[d[i] >> 8], 1);
            } else d[i] = -1;
        }
        __syncthreads();
        if (hist[tid] > 0) goffs[tid] = atomicAdd(&gcursor[tid], hist[tid]);
        __syncthreads();
#pragma unroll
        for (int i = 0; i < 8; ++i) {
            if (d[i] >= 0) {
                int b = d[i] >> 8;
                int p = goffs[b] + atomicAdd(&cnt2[b], 1);
                packed[(size_t)b * BCAP + p] = ((u32)d[i] << 16) | (u32)s[i];
            }
        }
        return;
    }

    // ---- GEMM role: Yh[n] = (fp16)(X[n] @ W1 + b1)  (dinv applied later) --
    const int idx = blockIdx.x >> 1;
    const int base = idx * 16;
    const int nvec = 16 * IN_DIM / 4;
    const float4* X4 = reinterpret_cast<const float4*>(X + (size_t)base * IN_DIM);
    float4* xs4 = reinterpret_cast<float4*>(&xs[0][0]);
    for (int i = tid; i < nvec; i += 256) {
        int row = (i * 4) / IN_DIM;
        xs4[i] = (base + row < n_nodes) ? X4[i] : make_float4(0.f, 0.f, 0.f, 0.f);
    }
    __syncthreads();

    const int j = tid & 63;
    const int q = tid >> 6;
    float b = bias[j];
    float a0 = b, a1 = b, a2 = b, a3 = b;
#pragma unroll 4
    for (int k = 0; k < IN_DIM; ++k) {
        float w = W[k * 64 + j];  // coalesced wave load, L1-resident (32KB)
        a0 += w * xs[q * 4 + 0][k];
        a1 += w * xs[q * 4 + 1][k];
        a2 += w * xs[q * 4 + 2][k];
        a3 += w * xs[q * 4 + 3][k];
    }
    int n0 = base + q * 4;
    if (n0 + 0 < n_nodes) Yh[(size_t)(n0 + 0) * 64 + j] = __float2half(a0);
    if (n0 + 1 < n_nodes) Yh[(size_t)(n0 + 1) * 64 + j] = __float2half(a1);
    if (n0 + 2 < n_nodes) Yh[(size_t)(n0 + 2) * 64 + j] = __float2half(a2);
    if (n0 + 3 < n_nodes) Yh[(size_t)(n0 + 3) * 64 + j] = __float2half(a3);
}

// ---- fine pass: one block per coarse bucket -------------------------------
// Build 256-dst x CAP u16 image in LDS (LDS atomics), stream out coalesced
// (each global line written exactly once). Also emits deg + dinv.
__global__ __launch_bounds__(256) void fine_kernel(
    const u32* __restrict__ packed, const int* __restrict__ gcursor,
    u16* __restrict__ ssorted, int* __restrict__ deg, float* __restrict__ dinv) {
    __shared__ u16 image[256 * CAP];  // 32 KB
    __shared__ int cur[256];
    const int b = blockIdx.x;
    const int tid = threadIdx.x;
    cur[tid] = 0;
    __syncthreads();
    const int cnt = gcursor[b];
    const u32* pp = packed + (size_t)b * BCAP;
    for (int i = tid; i < cnt; i += 256) {
        u32 p = pp[i];
        int dl = (p >> 16) & 255;
        int pos = atomicAdd(&cur[dl], 1);
        if (pos < CAP) image[dl * CAP + pos] = (u16)(p & 0xffff);
    }
    __syncthreads();
    // stream image to global (holes carry garbage; never read past deg)
    const u32* im32 = reinterpret_cast<const u32*>(image);
    u32* out32 = reinterpret_cast<u32*>(ssorted) + (size_t)b * (256 * CAP / 2);
    for (int i = tid; i < 256 * CAP / 2; i += 256) out32[i] = im32[i];
    int d = b * 256 + tid;
    if (d < N_NODES) {
        int c = cur[tid];
        deg[d] = c;
        dinv[d] = rsqrtf(fmaxf((float)c, 1.0f));
    }
}

// ---- scale (H1h *= dinv) + graph bounds -----------------------------------
__global__ __launch_bounds__(256) void scale_bounds_kernel(
    __half* __restrict__ H1h, const float* __restrict__ dinv, int n_nodes,
    const int* __restrict__ batch, int* __restrict__ gstart, int n_graphs) {
    const int tid = threadIdx.x;
    if (blockIdx.x == gridDim.x - 1) {  // ---- bounds role ----
        for (int g = tid; g <= n_graphs; g += 256) {
            int lo = 0, hi = n_nodes;
            while (lo < hi) {
                int mid = (lo + hi) >> 1;
                if (batch[mid] < g) lo = mid + 1; else hi = mid;
            }
            gstart[g] = lo;
        }
        return;
    }
    __half2* H2 = reinterpret_cast<__half2*>(H1h);
    const size_t base2 = (size_t)blockIdx.x * 512;
#pragma unroll
    for (int k = 0; k < 2; ++k) {
        size_t el = base2 + (size_t)k * 256 + tid;
        int row = (int)(el >> 5);
        if (row < n_nodes) {
            float dv = dinv[row];
            float2 f = __half22float2(H2[el]);
            H2[el] = __floats2half2_rn(f.x * dv, f.y * dv);
        }
    }
}

// ---- gather unpack: uint4 = 8 halves -> 4 float2 accumulated --------------
__device__ __forceinline__ void acc_row(const uint4& v, float2& aa, float2& ab,
                                        float2& ac, float2& ad) {
    const __half2* hp = reinterpret_cast<const __half2*>(&v);
    float2 f;
    f = __half22float2(hp[0]); aa.x += f.x; aa.y += f.y;
    f = __half22float2(hp[1]); ab.x += f.x; ab.y += f.y;
    f = __half22float2(hp[2]); ac.x += f.x; ac.y += f.y;
    f = __half22float2(hp[3]); ad.x += f.x; ad.y += f.y;
}

// ---- fused agg(layer1) + gemm(layer2): 32 dst rows per block -------------
__global__ __launch_bounds__(256) void agg_gemm_kernel(
    const __half* __restrict__ H, const u16* __restrict__ ssorted,
    const int* __restrict__ deg, const float* __restrict__ dinv,
    const float* __restrict__ W, const float* __restrict__ bias,
    __half* __restrict__ Yh, int n_nodes) {
    __shared__ float xs[32][64];
    const int tid = threadIdx.x;
    const int lane = tid & 63;
    const int w = tid >> 6;
    const int lo = lane & 7;
    const int slot = w * 8 + (lane >> 3);
    const int base = blockIdx.x * 32;
    const uint4* H16 = reinterpret_cast<const uint4*>(H);

    int node = base + slot;
    float2 aa = make_float2(0.f, 0.f), ab = make_float2(0.f, 0.f);
    float2 ac = make_float2(0.f, 0.f), ad = make_float2(0.f, 0.f);
    if (node < n_nodes) {
        int dg = min(deg[node], CAP);
        const u16* sp = ssorted + (size_t)node * CAP;
        int i = 0;
        for (; i + 3 < dg; i += 4) {
            ushort4 s4 = *reinterpret_cast<const ushort4*>(sp + i);
            uint4 v0 = H16[(size_t)s4.x * 8 + lo];
            uint4 v1 = H16[(size_t)s4.y * 8 + lo];
            uint4 v2 = H16[(size_t)s4.z * 8 + lo];
            uint4 v3 = H16[(size_t)s4.w * 8 + lo];
            acc_row(v0, aa, ab, ac, ad);
            acc_row(v1, aa, ab, ac, ad);
            acc_row(v2, aa, ab, ac, ad);
            acc_row(v3, aa, ab, ac, ad);
        }
        for (; i < dg; ++i) {
            uint4 v = H16[(size_t)sp[i] * 8 + lo];
            acc_row(v, aa, ab, ac, ad);
        }
        float dv = dinv[node];
        *reinterpret_cast<float4*>(&xs[slot][8 * lo]) =
            make_float4(fmaxf(aa.x * dv, 0.f), fmaxf(aa.y * dv, 0.f),
                        fmaxf(ab.x * dv, 0.f), fmaxf(ab.y * dv, 0.f));
        *reinterpret_cast<float4*>(&xs[slot][8 * lo + 4]) =
            make_float4(fmaxf(ac.x * dv, 0.f), fmaxf(ac.y * dv, 0.f),
                        fmaxf(ad.x * dv, 0.f), fmaxf(ad.y * dv, 0.f));
    } else {
        *reinterpret_cast<float4*>(&xs[slot][8 * lo]) = make_float4(0.f, 0.f, 0.f, 0.f);
        *reinterpret_cast<float4*>(&xs[slot][8 * lo + 4]) = make_float4(0.f, 0.f, 0.f, 0.f);
    }
    __syncthreads();

    float b = bias[lane];
    float c[8];
#pragma unroll
    for (int r = 0; r < 8; ++r) c[r] = b;
#pragma unroll 4
    for (int k = 0; k < 64; ++k) {
        float wv = W[k * 64 + lane];
#pragma unroll
        for (int r = 0; r < 8; ++r) c[r] += wv * xs[w * 8 + r][k];
    }
    int n0 = base + w * 8;
#pragma unroll
    for (int r = 0; r < 8; ++r)
        if (n0 + r < n_nodes)
            Yh[(size_t)(n0 + r) * 64 + lane] = __float2half(c[r] * dinv[n0 + r]);
}

// ---- fused layer-2 agg + pool: 2 blocks/graph, 32 node-slots/block -------
__global__ __launch_bounds__(256) void agg2_pool_kernel(
    const __half* __restrict__ H, const u16* __restrict__ ssorted,
    const int* __restrict__ deg, const float* __restrict__ dinv,
    const int* __restrict__ gstart, float* __restrict__ out) {
    __shared__ float part[32][64];
    const int g = blockIdx.x >> 1;
    const int sbid = blockIdx.x & 1;
    const int tid = threadIdx.x;
    const int lane = tid & 63;
    const int w = tid >> 6;
    const int lo = lane & 7;
    const int slot = w * 8 + (lane >> 3);
    const uint4* H16 = reinterpret_cast<const uint4*>(H);
    const int beg = gstart[g], end = gstart[g + 1];

    float2 pa = make_float2(0.f, 0.f), pb = make_float2(0.f, 0.f);
    float2 pc = make_float2(0.f, 0.f), pd = make_float2(0.f, 0.f);
    for (int node = beg + sbid * 32 + slot; node < end; node += 64) {
        int dg = min(deg[node], CAP);
        const u16* sp = ssorted + (size_t)node * CAP;
        float2 aa = make_float2(0.f, 0.f), ab = make_float2(0.f, 0.f);
        float2 ac = make_float2(0.f, 0.f), ad = make_float2(0.f, 0.f);
        int i = 0;
        for (; i + 3 < dg; i += 4) {
            ushort4 s4 = *reinterpret_cast<const ushort4*>(sp + i);
            uint4 v0 = H16[(size_t)s4.x * 8 + lo];
            uint4 v1 = H16[(size_t)s4.y * 8 + lo];
            uint4 v2 = H16[(size_t)s4.z * 8 + lo];
            uint4 v3 = H16[(size_t)s4.w * 8 + lo];
            acc_row(v0, aa, ab, ac, ad);
            acc_row(v1, aa, ab, ac, ad);
            acc_row(v2, aa, ab, ac, ad);
            acc_row(v3, aa, ab, ac, ad);
        }
        for (; i < dg; ++i) {
            uint4 v = H16[(size_t)sp[i] * 8 + lo];
            acc_row(v, aa, ab, ac, ad);
        }
        float dv = dinv[node];
        pa.x += fmaxf(aa.x * dv, 0.f); pa.y += fmaxf(aa.y * dv, 0.f);
        pb.x += fmaxf(ab.x * dv, 0.f); pb.y += fmaxf(ab.y * dv, 0.f);
        pc.x += fmaxf(ac.x * dv, 0.f); pc.y += fmaxf(ac.y * dv, 0.f);
        pd.x += fmaxf(ad.x * dv, 0.f); pd.y += fmaxf(ad.y * dv, 0.f);
    }
    *reinterpret_cast<float4*>(&part[slot][8 * lo]) = make_float4(pa.x, pa.y, pb.x, pb.y);
    *reinterpret_cast<float4*>(&part[slot][8 * lo + 4]) = make_float4(pc.x, pc.y, pd.x, pd.y);
    __syncthreads();
    if (tid < 64) {
        float s = 0.f;
#pragma unroll
        for (int r = 0; r < 32; ++r) s += part[r][tid];
        atomicAdd(&out[(size_t)g * 64 + tid], s);
    }
}

// ---- out /= count (from gstart) ------------------------------------------
__global__ void div_kernel(float* __restrict__ out, const int* __restrict__ gstart,
                           int n) {
    int t = blockIdx.x * blockDim.x + threadIdx.x;
    if (t < n) {
        int g = t >> 6;
        out[t] /= fmaxf((float)(gstart[g + 1] - gstart[g]), 1.0f);
    }
}

extern "C" void kernel_launch(void* const* d_in, const int* in_sizes, int n_in,
                              void* d_out, int out_size, void* d_ws, size_t ws_size,
                              hipStream_t stream) {
    const float* x     = (const float*)d_in[0];
    const int*   ei    = (const int*)d_in[1];   // [2, E]
    const int*   batch = (const int*)d_in[2];
    const float* W1    = (const float*)d_in[3];
    const float* b1    = (const float*)d_in[4];
    const float* W2    = (const float*)d_in[5];
    const float* b2    = (const float*)d_in[6];
    float* out = (float*)d_out;

    const int* srcp = ei;
    const int* dstp = ei + N_EDGES;

    // workspace layout (~23.7 MB)
    __half* H1h     = (__half*)d_ws;                        // 50000*64 fp16
    __half* H2h     = H1h + (size_t)N_NODES * 64;           // 50000*64 fp16
    float*  dinv    = (float*)(H2h + (size_t)N_NODES * 64); // 50000
    int*    deg     = (int*)(dinv + N_NODES);               // 50000
    u16*    ssorted = (u16*)(deg + N_NODES);                // 196*256*64 u16
    u32*    packed  = (u32*)(ssorted + (size_t)NB * 256 * CAP);  // 196*5120 u32
    int*    gcursor = (int*)(packed + (size_t)NB * BCAP);   // 256
    int*    gstart  = gcursor + 256;                        // 513

    hipMemsetAsync(gcursor, 0, 256 * sizeof(int), stream);
    hipMemsetAsync(out, 0, (size_t)NUM_GRAPHS * OUT_DIM * sizeof(float), stream);

    // hybrid: layer-1 GEMM (even) || coarse edge bucket-sort (odd)
    gemm1_fill_kernel<<<2 * ((N_NODES + 15) / 16), 256, 0, stream>>>(
        x, W1, b1, H1h, N_NODES, srcp, dstp, gcursor, packed, N_EDGES);

    // fine sort: LDS bucket image -> coalesced ssorted; emits deg + dinv
    fine_kernel<<<NB, 256, 0, stream>>>(packed, gcursor, ssorted, deg, dinv);

    // H1h *= dinv + gstart bounds
    scale_bounds_kernel<<<(N_NODES + 15) / 16 + 1, 256, 0, stream>>>(
        H1h, dinv, N_NODES, batch, gstart, NUM_GRAPHS);

    // fused layer-1 aggregation + layer-2 GEMM (8-node/16B gather)
    agg_gemm_kernel<<<(N_NODES + 31) / 32, 256, 0, stream>>>(
        H1h, ssorted, deg, dinv, W2, b2, H2h, N_NODES);

    // fused layer-2 aggregation + mean pool (2 blocks/graph, atomic combine)
    agg2_pool_kernel<<<2 * NUM_GRAPHS, 256, 0, stream>>>(
        H2h, ssorted, deg, dinv, gstart, out);
    div_kernel<<<(NUM_GRAPHS * OUT_DIM + 255) / 256, 256, 0, stream>>>(
        out, gstart, NUM_GRAPHS * OUT_DIM);
}

// Round 15
// 173.343 us; speedup vs baseline: 1.0707x; 1.0707x over previous
//
#include <hip/hip_runtime.h>
#include <hip/hip_fp16.h>

#define N_NODES 50000
#define N_EDGES 800000
#define IN_DIM 128
#define HID_DIM 64
#define OUT_DIM 64
#define NUM_GRAPHS 512
#define CAP 64      // per-dst bucket capacity (max deg ~45)
#define NB 196      // coarse buckets = dst>>8
#define BCAP 5120   // coarse bucket capacity (avg 4082, +16 sigma)
#define FILL_T 2048 // edges per coarse-fill block
#define NFILL ((N_EDGES + FILL_T - 1) / FILL_T)  // 391
#define GEMM_BLKS ((N_NODES + 31) / 32)          // 1563

typedef unsigned short u16;
typedef unsigned int u32;

// ---- hybrid: even blocks = layer-1 GEMM (32 nodes, unscaled fp16 out),
//              odd blocks  = coarse bucket-sort (block-exclusive runs) ------
__global__ __launch_bounds__(256) void gemm1_fill_kernel(
    const float* __restrict__ X, const float* __restrict__ W,
    const float* __restrict__ bias, __half* __restrict__ Yh, int n_nodes,
    const int* __restrict__ src, const int* __restrict__ dst,
    int* __restrict__ gcursor, u32* __restrict__ packed, int n_edges) {
    __shared__ float xs[32][IN_DIM];          // 16 KB
    __shared__ int hist[256], cnt2[256], goffs[256];
    const int tid = threadIdx.x;

    if (blockIdx.x & 1) {  // ---- coarse fill role ----
        const int fb = blockIdx.x >> 1;
        if (fb >= NFILL) return;
        hist[tid] = 0; cnt2[tid] = 0;
        __syncthreads();
        const int base = fb * FILL_T;
        int d[8], s[8];
#pragma unroll
        for (int i = 0; i < 8; ++i) {
            int e = base + i * 256 + tid;
            if (e < n_edges) {
                d[i] = dst[e]; s[i] = src[e];
                atomicAdd(&hist[d[i] >> 8], 1);
            } else d[i] = -1;
        }
        __syncthreads();
        if (hist[tid] > 0) goffs[tid] = atomicAdd(&gcursor[tid], hist[tid]);
        __syncthreads();
#pragma unroll
        for (int i = 0; i < 8; ++i) {
            if (d[i] >= 0) {
                int b = d[i] >> 8;
                int p = goffs[b] + atomicAdd(&cnt2[b], 1);
                packed[(size_t)b * BCAP + p] = ((u32)d[i] << 16) | (u32)s[i];
            }
        }
        return;
    }

    // ---- GEMM role: Yh[n] = (fp16)(X[n] @ W1 + b1), 8 rows/wave ----------
    const int idx = blockIdx.x >> 1;
    if (idx >= GEMM_BLKS) return;
    const int base = idx * 32;
    const int nvec = 32 * IN_DIM / 4;
    const float4* X4 = reinterpret_cast<const float4*>(X + (size_t)base * IN_DIM);
    float4* xs4 = reinterpret_cast<float4*>(&xs[0][0]);
    for (int i = tid; i < nvec; i += 256) {
        int row = i / (IN_DIM / 4);
        xs4[i] = (base + row < n_nodes) ? X4[i] : make_float4(0.f, 0.f, 0.f, 0.f);
    }
    __syncthreads();

    const int j = tid & 63;
    const int w = tid >> 6;
    float b = bias[j];
    float c[8];
#pragma unroll
    for (int r = 0; r < 8; ++r) c[r] = b;
#pragma unroll 4
    for (int k = 0; k < IN_DIM; ++k) {
        float wv = W[k * 64 + j];  // 256B/wave, L1-resident; feeds 8 FMAs
#pragma unroll
        for (int r = 0; r < 8; ++r) c[r] += wv * xs[w * 8 + r][k];
    }
    int n0 = base + w * 8;
#pragma unroll
    for (int r = 0; r < 8; ++r)
        if (n0 + r < n_nodes)
            Yh[(size_t)(n0 + r) * 64 + j] = __float2half(c[r]);
}

// ---- fine pass: 2 blocks per coarse bucket (128 dst nodes each) ----------
// LDS bucket image -> coalesced ssorted; emits deg+dinv; scales own H1h rows
// in place (replaces the old scale pass). Last block: gstart bounds.
__global__ __launch_bounds__(256) void fine_kernel(
    const u32* __restrict__ packed, const int* __restrict__ gcursor,
    u16* __restrict__ ssorted, int* __restrict__ deg, float* __restrict__ dinv,
    __half* __restrict__ H1h,
    const int* __restrict__ batch, int* __restrict__ gstart, int n_graphs) {
    __shared__ u16 image[128 * CAP];  // 16 KB
    __shared__ int cur[128];
    __shared__ float ds[128];
    const int tid = threadIdx.x;

    if (blockIdx.x == 2 * NB) {  // ---- bounds role ----
        for (int g = tid; g <= n_graphs; g += 256) {
            int lo = 0, hi = N_NODES;
            while (lo < hi) {
                int mid = (lo + hi) >> 1;
                if (batch[mid] < g) lo = mid + 1; else hi = mid;
            }
            gstart[g] = lo;
        }
        return;
    }

    const int b = blockIdx.x >> 1;
    const int half = blockIdx.x & 1;
    if (tid < 128) cur[tid] = 0;
    __syncthreads();
    const int cnt = gcursor[b];
    const u32* pp = packed + (size_t)b * BCAP;
    for (int i = tid; i < cnt; i += 256) {
        u32 p = pp[i];
        int dl = (p >> 16) & 255;
        if ((dl >> 7) == half) {
            int loc = dl & 127;
            int pos = atomicAdd(&cur[loc], 1);
            if (pos < CAP) image[loc * CAP + pos] = (u16)(p & 0xffff);
        }
    }
    __syncthreads();
    const int nbase = b * 256 + half * 128;  // first node of this block
    if (tid < 128) {
        int c = cur[tid];
        float dv = rsqrtf(fmaxf((float)c, 1.0f));
        ds[tid] = dv;
        int d = nbase + tid;
        if (d < N_NODES) { deg[d] = c; dinv[d] = dv; }
    }
    __syncthreads();
    // stream bucket image out (each line written exactly once, coalesced)
    const u32* im32 = reinterpret_cast<const u32*>(image);
    u32* out32 = reinterpret_cast<u32*>(ssorted) + (size_t)nbase * (CAP / 2);
    for (int i = tid; i < 128 * CAP / 2; i += 256) out32[i] = im32[i];
    // scale own H1h rows in place: H1h[node] *= dinv[node]  (coalesced)
    __half2* H2 = reinterpret_cast<__half2*>(H1h) + (size_t)nbase * 32;
    const int lim = min(128, N_NODES - nbase) * 32;
    for (int i = tid; i < lim; i += 256) {
        float dv = ds[i >> 5];
        float2 f = __half22float2(H2[i]);
        H2[i] = __floats2half2_rn(f.x * dv, f.y * dv);
    }
}

// ---- gather unpack: uint4 = 8 halves -> 4 float2 accumulated --------------
__device__ __forceinline__ void acc_row(const uint4& v, float2& aa, float2& ab,
                                        float2& ac, float2& ad) {
    const __half2* hp = reinterpret_cast<const __half2*>(&v);
    float2 f;
    f = __half22float2(hp[0]); aa.x += f.x; aa.y += f.y;
    f = __half22float2(hp[1]); ab.x += f.x; ab.y += f.y;
    f = __half22float2(hp[2]); ac.x += f.x; ac.y += f.y;
    f = __half22float2(hp[3]); ad.x += f.x; ad.y += f.y;
}

// ---- fused agg(layer1) + gemm(layer2): 32 dst rows per block -------------
__global__ __launch_bounds__(256) void agg_gemm_kernel(
    const __half* __restrict__ H, const u16* __restrict__ ssorted,
    const int* __restrict__ deg, const float* __restrict__ dinv,
    const float* __restrict__ W, const float* __restrict__ bias,
    __half* __restrict__ Yh, int n_nodes) {
    __shared__ float xs[32][64];
    const int tid = threadIdx.x;
    const int lane = tid & 63;
    const int w = tid >> 6;
    const int lo = lane & 7;
    const int slot = w * 8 + (lane >> 3);
    const int base = blockIdx.x * 32;
    const uint4* H16 = reinterpret_cast<const uint4*>(H);

    int node = base + slot;
    float2 aa = make_float2(0.f, 0.f), ab = make_float2(0.f, 0.f);
    float2 ac = make_float2(0.f, 0.f), ad = make_float2(0.f, 0.f);
    if (node < n_nodes) {
        int dg = min(deg[node], CAP);
        const u16* sp = ssorted + (size_t)node * CAP;
        int i = 0;
        for (; i + 3 < dg; i += 4) {
            ushort4 s4 = *reinterpret_cast<const ushort4*>(sp + i);
            uint4 v0 = H16[(size_t)s4.x * 8 + lo];
            uint4 v1 = H16[(size_t)s4.y * 8 + lo];
            uint4 v2 = H16[(size_t)s4.z * 8 + lo];
            uint4 v3 = H16[(size_t)s4.w * 8 + lo];
            acc_row(v0, aa, ab, ac, ad);
            acc_row(v1, aa, ab, ac, ad);
            acc_row(v2, aa, ab, ac, ad);
            acc_row(v3, aa, ab, ac, ad);
        }
        for (; i < dg; ++i) {
            uint4 v = H16[(size_t)sp[i] * 8 + lo];
            acc_row(v, aa, ab, ac, ad);
        }
        float dv = dinv[node];
        *reinterpret_cast<float4*>(&xs[slot][8 * lo]) =
            make_float4(fmaxf(aa.x * dv, 0.f), fmaxf(aa.y * dv, 0.f),
                        fmaxf(ab.x * dv, 0.f), fmaxf(ab.y * dv, 0.f));
        *reinterpret_cast<float4*>(&xs[slot][8 * lo + 4]) =
            make_float4(fmaxf(ac.x * dv, 0.f), fmaxf(ac.y * dv, 0.f),
                        fmaxf(ad.x * dv, 0.f), fmaxf(ad.y * dv, 0.f));
    } else {
        *reinterpret_cast<float4*>(&xs[slot][8 * lo]) = make_float4(0.f, 0.f, 0.f, 0.f);
        *reinterpret_cast<float4*>(&xs[slot][8 * lo + 4]) = make_float4(0.f, 0.f, 0.f, 0.f);
    }
    __syncthreads();

    float b = bias[lane];
    float c[8];
#pragma unroll
    for (int r = 0; r < 8; ++r) c[r] = b;
#pragma unroll 4
    for (int k = 0; k < 64; ++k) {
        float wv = W[k * 64 + lane];
#pragma unroll
        for (int r = 0; r < 8; ++r) c[r] += wv * xs[w * 8 + r][k];
    }
    int n0 = base + w * 8;
#pragma unroll
    for (int r = 0; r < 8; ++r)
        if (n0 + r < n_nodes)
            Yh[(size_t)(n0 + r) * 64 + lane] = __float2half(c[r] * dinv[n0 + r]);
}

// ---- fused layer-2 agg + mean pool: 1 block/graph, 512 thr, direct store -
__global__ __launch_bounds__(512) void agg2_pool_kernel(
    const __half* __restrict__ H, const u16* __restrict__ ssorted,
    const int* __restrict__ deg, const float* __restrict__ dinv,
    const int* __restrict__ gstart, float* __restrict__ out) {
    __shared__ float part[64][64];  // 16 KB
    const int g = blockIdx.x;
    const int tid = threadIdx.x;
    const int lane = tid & 63;
    const int w = tid >> 6;             // 0..7
    const int lo = lane & 7;
    const int slot = w * 8 + (lane >> 3);  // 0..63
    const uint4* H16 = reinterpret_cast<const uint4*>(H);
    const int beg = gstart[g], end = gstart[g + 1];

    float2 pa = make_float2(0.f, 0.f), pb = make_float2(0.f, 0.f);
    float2 pc = make_float2(0.f, 0.f), pd = make_float2(0.f, 0.f);
    for (int node = beg + slot; node < end; node += 64) {
        int dg = min(deg[node], CAP);
        const u16* sp = ssorted + (size_t)node * CAP;
        float2 aa = make_float2(0.f, 0.f), ab = make_float2(0.f, 0.f);
        float2 ac = make_float2(0.f, 0.f), ad = make_float2(0.f, 0.f);
        int i = 0;
        for (; i + 3 < dg; i += 4) {
            ushort4 s4 = *reinterpret_cast<const ushort4*>(sp + i);
            uint4 v0 = H16[(size_t)s4.x * 8 + lo];
            uint4 v1 = H16[(size_t)s4.y * 8 + lo];
            uint4 v2 = H16[(size_t)s4.z * 8 + lo];
            uint4 v3 = H16[(size_t)s4.w * 8 + lo];
            acc_row(v0, aa, ab, ac, ad);
            acc_row(v1, aa, ab, ac, ad);
            acc_row(v2, aa, ab, ac, ad);
            acc_row(v3, aa, ab, ac, ad);
        }
        for (; i < dg; ++i) {
            uint4 v = H16[(size_t)sp[i] * 8 + lo];
            acc_row(v, aa, ab, ac, ad);
        }
        float dv = dinv[node];
        pa.x += fmaxf(aa.x * dv, 0.f); pa.y += fmaxf(aa.y * dv, 0.f);
        pb.x += fmaxf(ab.x * dv, 0.f); pb.y += fmaxf(ab.y * dv, 0.f);
        pc.x += fmaxf(ac.x * dv, 0.f); pc.y += fmaxf(ac.y * dv, 0.f);
        pd.x += fmaxf(ad.x * dv, 0.f); pd.y += fmaxf(ad.y * dv, 0.f);
    }
    *reinterpret_cast<float4*>(&part[slot][8 * lo]) = make_float4(pa.x, pa.y, pb.x, pb.y);
    *reinterpret_cast<float4*>(&part[slot][8 * lo + 4]) = make_float4(pc.x, pc.y, pd.x, pd.y);
    __syncthreads();
    if (tid < 64) {
        float s = 0.f;
#pragma unroll
        for (int r = 0; r < 64; ++r) s += part[r][tid];
        out[(size_t)g * 64 + tid] = s / fmaxf((float)(end - beg), 1.0f);
    }
}

extern "C" void kernel_launch(void* const* d_in, const int* in_sizes, int n_in,
                              void* d_out, int out_size, void* d_ws, size_t ws_size,
                              hipStream_t stream) {
    const float* x     = (const float*)d_in[0];
    const int*   ei    = (const int*)d_in[1];   // [2, E]
    const int*   batch = (const int*)d_in[2];
    const float* W1    = (const float*)d_in[3];
    const float* b1    = (const float*)d_in[4];
    const float* W2    = (const float*)d_in[5];
    const float* b2    = (const float*)d_in[6];
    float* out = (float*)d_out;

    const int* srcp = ei;
    const int* dstp = ei + N_EDGES;

    // workspace layout (~23.7 MB)
    __half* H1h     = (__half*)d_ws;                        // 50000*64 fp16
    __half* H2h     = H1h + (size_t)N_NODES * 64;           // 50000*64 fp16
    float*  dinv    = (float*)(H2h + (size_t)N_NODES * 64); // 50000
    int*    deg     = (int*)(dinv + N_NODES);               // 50000
    u16*    ssorted = (u16*)(deg + N_NODES);                // 50176*CAP u16
    u32*    packed  = (u32*)(ssorted + (size_t)NB * 256 * CAP);  // 196*5120 u32
    int*    gcursor = (int*)(packed + (size_t)NB * BCAP);   // 256
    int*    gstart  = gcursor + 256;                        // 513

    hipMemsetAsync(gcursor, 0, 256 * sizeof(int), stream);

    // hybrid: layer-1 GEMM (even, 32 nodes/block) || coarse edge sort (odd)
    gemm1_fill_kernel<<<2 * GEMM_BLKS, 256, 0, stream>>>(
        x, W1, b1, H1h, N_NODES, srcp, dstp, gcursor, packed, N_EDGES);

    // fine sort (2 blocks/bucket) + deg/dinv + in-place H1h scale + bounds
    fine_kernel<<<2 * NB + 1, 256, 0, stream>>>(
        packed, gcursor, ssorted, deg, dinv, H1h, batch, gstart, NUM_GRAPHS);

    // fused layer-1 aggregation + layer-2 GEMM (8-node/16B gather)
    agg_gemm_kernel<<<(N_NODES + 31) / 32, 256, 0, stream>>>(
        H1h, ssorted, deg, dinv, W2, b2, H2h, N_NODES);

    // fused layer-2 aggregation + mean pool (1 block/graph, direct store)
    agg2_pool_kernel<<<NUM_GRAPHS, 512, 0, stream>>>(
        H2h, ssorted, deg, dinv, gstart, out);
}